// Round 14
// baseline (276.743 us; speedup 1.0000x reference)
//
#include <hip/hip_runtime.h>
#include <hip/hip_bf16.h>

typedef __bf16 bf16x8 __attribute__((ext_vector_type(8)));
typedef float f32x4 __attribute__((ext_vector_type(4)));
typedef unsigned int u32;
typedef unsigned short u16;
typedef u32 u32x4 __attribute__((ext_vector_type(4)));
typedef u16 u16x4 __attribute__((ext_vector_type(4)));
typedef u16 u16x8 __attribute__((ext_vector_type(8)));

// manual RNE f32->bf16 (prep kernels)
__device__ __forceinline__ u16 f2bf(float x) {
  u32 u = __float_as_uint(x);
  return (u16)((u + 0x7FFFu + ((u >> 16) & 1u)) >> 16);
}
// compiler cast (hot path; lowers to packed cvt)
__device__ __forceinline__ u16 cvt_bf16(float x) {
  __bf16 h = (__bf16)x;
  return __builtin_bit_cast(u16, h);
}
__device__ __forceinline__ float bf2f(u16 h) {
  return __uint_as_float((u32)h << 16);
}
__device__ __forceinline__ bf16x8 cvt8(float4 a, float4 b) {
  u16x8 o = {cvt_bf16(a.x), cvt_bf16(a.y), cvt_bf16(a.z), cvt_bf16(a.w),
             cvt_bf16(b.x), cvt_bf16(b.y), cvt_bf16(b.z), cvt_bf16(b.w)};
  return __builtin_bit_cast(bf16x8, o);
}
__device__ __forceinline__ bf16x8 ld_frag_glb(const u16* p) {
  u32x4 v = *(const u32x4*)p;
  return __builtin_bit_cast(bf16x8, v);
}

// ---------------------------------------------------------------------------
// prep_w (R10/R12-proven, UNCHANGED):
// wfA (128 KB): W2a K=256 N=256 as MFMA A-fragments:
//   wfA[((ntg*8+ks)*64+lane)*8+q] = W2a[ks*32+(lane>>4)*8+q][ntg*16+(lane&15)]
// wfB2 (32 KB): W2b fragments, PI-PERMUTED k-order:
//   element (lane(c,g), q) = W2b[64w+32t2+pi(g,q)][dt*16+c],
//   pi(g,q) = q<4 ? 4g+q : 16+4g+(q-4).
// ---------------------------------------------------------------------------
__global__ void prep_w_kernel(const float* __restrict__ W2a, const float* __restrict__ W2b,
                              u16* __restrict__ wfA, u16* __restrict__ wfB2) {
  int t = blockIdx.x * 256 + threadIdx.x;
  if (t < 8192) {  // wfA: 16 ntg * 8 ks * 64 lanes
    int lane = t & 63;
    int ks = (t >> 6) & 7;
    int ntg = t >> 9;
    int col = (ntg << 4) + (lane & 15);
    int kb = (ks << 5) + ((lane >> 4) << 3);
#pragma unroll
    for (int q = 0; q < 8; ++q)
      wfA[t * 8 + q] = f2bf(W2a[(kb + q) * 256 + col]);
  } else if (t < 10240) {  // wfB2: 4 w * 2 t2 * 4 dt * 64 lanes
    int t2i = t - 8192;
    int lane = t2i & 63;
    int dt = (t2i >> 6) & 3;
    int tt = (t2i >> 8) & 1;
    int w = t2i >> 9;
    int g = lane >> 4, c = lane & 15;
    int col = (dt << 4) + c;
#pragma unroll
    for (int q = 0; q < 8; ++q) {
      int pi = (q < 4) ? (g * 4 + q) : (16 + g * 4 + (q - 4));
      int n = w * 64 + tt * 32 + pi;
      wfB2[t2i * 8 + q] = f2bf(W2b[n * 64 + col]);
    }
  }
}

// ---------------------------------------------------------------------------
// out1: R1-proven, SEPARATE kernel (fusion thrashes cache: R4/R5/R11).
// Launched before out2 (puts emb2 -- 134 MB, L3-fits -- into L3).
// ---------------------------------------------------------------------------
__global__ __launch_bounds__(256) void out1_kernel(
    const float* __restrict__ emb1, const float* __restrict__ emb2,
    const float* __restrict__ W1a, const float* __restrict__ b1a,
    const float* __restrict__ W1b, const float* __restrict__ b1b,
    float* __restrict__ out1) {
  int bi = blockIdx.x;
  int t = threadIdx.x;
  __shared__ float smax[4][64];
  __shared__ float smin[4][64];
  __shared__ float cat1[192];
  __shared__ float h[128];

  int d = t & 63, q = t >> 6;
  const float* base = emb2 + (size_t)bi * 256 * 64;
  float vmax = -INFINITY, vmin = INFINITY;
  for (int j = q; j < 256; j += 4) {
    float v = base[j * 64 + d];
    vmax = fmaxf(vmax, v);
    vmin = fminf(vmin, v);
  }
  smax[q][d] = vmax;
  smin[q][d] = vmin;
  __syncthreads();
  if (t < 64) {
    float mx = fmaxf(fmaxf(smax[0][t], smax[1][t]), fmaxf(smax[2][t], smax[3][t]));
    float mn = fminf(fminf(smin[0][t], smin[1][t]), fminf(smin[2][t], smin[3][t]));
    cat1[t] = emb1[bi * 64 + t];
    cat1[64 + t] = mx;
    cat1[128 + t] = mn;
  }
  __syncthreads();
  if (t < 128) {
    float acc = b1a[t];
    for (int k = 0; k < 192; ++k) acc += cat1[k] * W1a[k * 128 + t];
    h[t] = fmaxf(acc, 0.f);
  }
  __syncthreads();
  if (t < 64) {
    float acc = b1b[t];
    for (int k = 0; k < 128; ++k) acc += h[k] * W1b[k * 64 + t];
    out1[bi * 64 + t] = acc;
  }
}

// ---------------------------------------------------------------------------
// out2: one block = (b, i, j-tile of 64). NO LDS STAGING, NO STAGE BARRIERS.
// GEMM1 A-fragments (X) are loaded DIRECTLY from global (emb2 is L3-resident,
// emb1 L2-resident) as per-lane 2x float4 + cvt. Long-latency frags hoisted:
//   s1 (ks=2,3): emb2[b,j,i,:] 64KB-stride gather -> 8 indep loads, first.
//   s2 (ks=4,5): e1[b,i] broadcast, shared across all m (load once).
//   s0 (ks=0,1), s3 (ks=6,7): coalesced rows, loaded just-in-time.
// GEMM2 in registers (R12-proven pi-packing). LDS = 24 KB bf16 exchange,
// ONE barrier per block. __launch_bounds__(256,2): cap 256 VGPR, no spill
// expected (~150-190); spill tripwire = WRITE_SIZE > 131.1 MB.
// ---------------------------------------------------------------------------
__global__ __launch_bounds__(256, 2) void out2_kernel(
    const float* __restrict__ emb1, const float* __restrict__ emb2,
    const float* __restrict__ b2a, const float* __restrict__ b2b,
    const u16* __restrict__ wfA, const u16* __restrict__ wfB2,
    float* __restrict__ out2) {
  __shared__ __align__(16) u16 SH[12288];  // 24 KB exchange only

  int blk = blockIdx.x;
  int b = blk >> 10;
  int i = (blk >> 2) & 255;
  int j0 = (blk & 3) << 6;
  int t = threadIdx.x;
  int lane = t & 63;
  int w = t >> 6;
  int lr = lane & 15;
  int lg = lane >> 4;

  // ---- hoisted long-latency X-fragments ----
  // s1 (ks=2,3): X col k=64+kk*32+lg*8+q = emb2[b, j0+16m+lr, i, kk*32+lg*8+q]
  bf16x8 xs1[4][2];
#pragma unroll
  for (int m = 0; m < 4; ++m) {
    const float* p = emb2 + ((((size_t)(b << 8) + j0 + (m << 4) + lr) << 8) + i) * 64 + (lg << 3);
#pragma unroll
    for (int kk = 0; kk < 2; ++kk)
      xs1[m][kk] = cvt8(*(const float4*)(p + (kk << 5)),
                        *(const float4*)(p + (kk << 5) + 4));
  }
  // s2 (ks=4,5): X col k=128+kk*32+lg*8+q = e1[b, i, kk*32+lg*8+q] (m-invariant)
  bf16x8 xs2[2];
  {
    const float* p = emb1 + (((b << 8) + i) << 6) + (lg << 3);
#pragma unroll
    for (int kk = 0; kk < 2; ++kk)
      xs2[kk] = cvt8(*(const float4*)(p + (kk << 5)),
                     *(const float4*)(p + (kk << 5) + 4));
  }

  // ---- GEMM1 (swapped): acc1[m][nt][e]: j = j0+16m+lr, n = 64w+16nt+4lg+e ----
  f32x4 acc1[4][4];
#pragma unroll
  for (int m = 0; m < 4; ++m)
#pragma unroll
    for (int nt = 0; nt < 4; ++nt) acc1[m][nt] = (f32x4){0.f, 0.f, 0.f, 0.f};

  auto g1step = [&](int ks, const bf16x8* a4) {
    bf16x8 bw[4];
#pragma unroll
    for (int nt = 0; nt < 4; ++nt)
      bw[nt] = ld_frag_glb(wfA + (size_t)((((w << 2) + nt) * 8 + ks) * 64 + lane) * 8);
#pragma unroll
    for (int m = 0; m < 4; ++m)
#pragma unroll
      for (int nt = 0; nt < 4; ++nt)
        acc1[m][nt] = __builtin_amdgcn_mfma_f32_16x16x32_bf16(bw[nt], a4[m], acc1[m][nt], 0, 0, 0);
  };

  // ks = 0,1: s0 = e1[b, j0+16m+lr, kk*32+lg*8+q] (coalesced-ish rows)
#pragma unroll
  for (int kk = 0; kk < 2; ++kk) {
    bf16x8 a4[4];
#pragma unroll
    for (int m = 0; m < 4; ++m) {
      const float* p = emb1 + (((b << 8) + j0 + (m << 4) + lr) << 6) + (lg << 3) + (kk << 5);
      a4[m] = cvt8(*(const float4*)p, *(const float4*)(p + 4));
    }
    g1step(kk, a4);
  }
  // ks = 6,7: s3 = emb2[b, i, j0+16m+lr, kk*32+lg*8+q] (contiguous 16KB slab)
#pragma unroll
  for (int kk = 0; kk < 2; ++kk) {
    bf16x8 a4[4];
#pragma unroll
    for (int m = 0; m < 4; ++m) {
      const float* p = emb2 + ((((size_t)(b << 8) + i) << 8) + j0 + (m << 4) + lr) * 64 +
                       (lg << 3) + (kk << 5);
      a4[m] = cvt8(*(const float4*)p, *(const float4*)(p + 4));
    }
    g1step(6 + kk, a4);
  }
  // ks = 4,5: s2 broadcast (hoisted)
#pragma unroll
  for (int kk = 0; kk < 2; ++kk) {
    bf16x8 a4[4] = {xs2[kk], xs2[kk], xs2[kk], xs2[kk]};
    g1step(4 + kk, a4);
  }
  // ks = 2,3: s1 gather (hoisted earliest -> longest latency cover)
#pragma unroll
  for (int kk = 0; kk < 2; ++kk) {
    bf16x8 a4[4] = {xs1[0][kk], xs1[1][kk], xs1[2][kk], xs1[3][kk]};
    g1step(2 + kk, a4);
  }

  // ---- GEMM2 in registers (pi-packing, R12-proven) ----
  f32x4 acc2[4][4];  // [m][dt]: d = 16dt+4lg+e, j = j0+16m+lr
#pragma unroll
  for (int m = 0; m < 4; ++m)
#pragma unroll
    for (int dt = 0; dt < 4; ++dt) acc2[m][dt] = (f32x4){0.f, 0.f, 0.f, 0.f};

#pragma unroll
  for (int t2 = 0; t2 < 2; ++t2) {
    int nbase = (w << 6) + (t2 << 5) + (lg << 2);
    float4 ba = *(const float4*)(b2a + nbase);
    float4 bb = *(const float4*)(b2a + nbase + 16);
    bf16x8 h[4];
#pragma unroll
    for (int m = 0; m < 4; ++m) {
      f32x4 pa = acc1[m][2 * t2];
      f32x4 pb = acc1[m][2 * t2 + 1];
      u16x8 hp = {cvt_bf16(fmaxf(pa[0] + ba.x, 0.f)), cvt_bf16(fmaxf(pa[1] + ba.y, 0.f)),
                  cvt_bf16(fmaxf(pa[2] + ba.z, 0.f)), cvt_bf16(fmaxf(pa[3] + ba.w, 0.f)),
                  cvt_bf16(fmaxf(pb[0] + bb.x, 0.f)), cvt_bf16(fmaxf(pb[1] + bb.y, 0.f)),
                  cvt_bf16(fmaxf(pb[2] + bb.z, 0.f)), cvt_bf16(fmaxf(pb[3] + bb.w, 0.f))};
      h[m] = __builtin_bit_cast(bf16x8, hp);
    }
#pragma unroll
    for (int dt = 0; dt < 4; ++dt) {
      bf16x8 wf = ld_frag_glb(wfB2 + (size_t)(((((w << 1) + t2) << 2) + dt) * 64 + lane) * 8);
#pragma unroll
      for (int m = 0; m < 4; ++m)
        acc2[m][dt] = __builtin_amdgcn_mfma_f32_16x16x32_bf16(wf, h[m], acc2[m][dt], 0, 0, 0);
    }
  }

  // ---- cross-wave reduction, BF16 partials: 12 tiles x 512B = 24 KB ----
  char* red = (char*)SH;
#pragma unroll
  for (int dt = 0; dt < 4; ++dt) {
    if (dt != w) {
      int s = dt - (dt > w ? 1 : 0);
#pragma unroll
      for (int m = 0; m < 4; ++m) {
        f32x4 p = acc2[m][dt];
        u16x4 o = {cvt_bf16(p[0]), cvt_bf16(p[1]), cvt_bf16(p[2]), cvt_bf16(p[3])};
        *(u16x4*)(red + (((w * 12 + s * 4 + m) << 9) + (lane << 3))) = o;
      }
    }
  }
  __syncthreads();  // the ONLY barrier in the block

  f32x4 accO[4];
#pragma unroll
  for (int m = 0; m < 4; ++m) {
    accO[m] = acc2[m][0];
#pragma unroll
    for (int dt = 1; dt < 4; ++dt)
      if (w == dt) accO[m] = acc2[m][dt];
  }
#pragma unroll
  for (int wp = 0; wp < 4; ++wp) {
    if (wp != w) {
      int s = w - (w > wp ? 1 : 0);
#pragma unroll
      for (int m = 0; m < 4; ++m) {
        u16x4 o = *(const u16x4*)(red + (((wp * 12 + s * 4 + m) << 9) + (lane << 3)));
        accO[m][0] += bf2f(o[0]);
        accO[m][1] += bf2f(o[1]);
        accO[m][2] += bf2f(o[2]);
        accO[m][3] += bf2f(o[3]);
      }
    }
  }

  // ---- store: j = j0+16m+lr, d = 16w+4lg+e ----
  float4 bias2 = *(const float4*)(b2b + (w << 4) + (lg << 2));
  float* obase = out2 + (((size_t)(b << 8) + i) * 256 + j0) * 64 + (w << 4) + (lg << 2);
#pragma unroll
  for (int m = 0; m < 4; ++m) {
    float4 v = {accO[m][0] + bias2.x, accO[m][1] + bias2.y,
                accO[m][2] + bias2.z, accO[m][3] + bias2.w};
    *(float4*)(obase + (size_t)((m << 4) + lr) * 64) = v;
  }
}

extern "C" void kernel_launch(void* const* d_in, const int* in_sizes, int n_in,
                              void* d_out, int out_size, void* d_ws, size_t ws_size,
                              hipStream_t stream) {
  const float* emb1 = (const float*)d_in[0];
  const float* emb2 = (const float*)d_in[1];
  const float* W1a  = (const float*)d_in[2];
  const float* b1a  = (const float*)d_in[3];
  const float* W1b  = (const float*)d_in[4];
  const float* b1b  = (const float*)d_in[5];
  const float* W2a  = (const float*)d_in[6];
  const float* b2a  = (const float*)d_in[7];
  const float* W2b  = (const float*)d_in[8];
  const float* b2b  = (const float*)d_in[9];

  float* out = (float*)d_out;
  u16* wfA  = (u16*)d_ws;            // 16*8*64*8 = 65536 u16 = 128 KB
  u16* wfB2 = wfA + 65536;           //  4*2*4*64*8 = 16384 u16 = 32 KB

  prep_w_kernel<<<40, 256, 0, stream>>>(W2a, W2b, wfA, wfB2);
  // out1 first: its full emb2 scan leaves emb2 (134 MB) L3-resident
  out1_kernel<<<2048, 256, 0, stream>>>(emb1, emb2, W1a, b1a, W1b, b1b, out);
  out2_kernel<<<8192, 256, 0, stream>>>(emb1, emb2, b2a, b2b, wfA, wfB2,
                                        out + 8 * 256 * 64);
}

// Round 15
// 152.608 us; speedup vs baseline: 1.8134x; 1.8134x over previous
//
#include <hip/hip_runtime.h>
#include <hip/hip_bf16.h>

typedef __bf16 bf16x8 __attribute__((ext_vector_type(8)));
typedef float f32x4 __attribute__((ext_vector_type(4)));
typedef unsigned int u32;
typedef unsigned short u16;
typedef u32 u32x4 __attribute__((ext_vector_type(4)));
typedef u16 u16x4 __attribute__((ext_vector_type(4)));
typedef u16 u16x8 __attribute__((ext_vector_type(8)));

// manual RNE f32->bf16 (prep kernels)
__device__ __forceinline__ u16 f2bf(float x) {
  u32 u = __float_as_uint(x);
  return (u16)((u + 0x7FFFu + ((u >> 16) & 1u)) >> 16);
}
// compiler cast (hot path)
__device__ __forceinline__ u16 cvt_bf16(float x) {
  __bf16 h = (__bf16)x;
  return __builtin_bit_cast(u16, h);
}
__device__ __forceinline__ float bf2f(u16 h) {
  return __uint_as_float((u32)h << 16);
}

__device__ __forceinline__ bf16x8 ld_frag_lds(const u16* base, int byteOff) {
  u32x4 v = *(const u32x4*)((const char*)base + byteOff);
  return __builtin_bit_cast(bf16x8, v);
}
__device__ __forceinline__ bf16x8 ld_frag_glb(const u16* p) {
  u32x4 v = *(const u32x4*)p;
  return __builtin_bit_cast(bf16x8, v);
}

// ---------------------------------------------------------------------------
// prep_w (R10/R12-proven, UNCHANGED):
// wfA (128 KB): W2a K=256 N=256 as MFMA A-fragments:
//   wfA[((ntg*8+ks)*64+lane)*8+q] = W2a[ks*32+(lane>>4)*8+q][ntg*16+(lane&15)]
// wfB2 (32 KB): W2b fragments, PI-PERMUTED k-order:
//   element (lane(c,g), q) = W2b[64w+32t2+pi(g,q)][dt*16+c],
//   pi(g,q) = q<4 ? 4g+q : 16+4g+(q-4).
// ---------------------------------------------------------------------------
__global__ void prep_w_kernel(const float* __restrict__ W2a, const float* __restrict__ W2b,
                              u16* __restrict__ wfA, u16* __restrict__ wfB2) {
  int t = blockIdx.x * 256 + threadIdx.x;
  if (t < 8192) {  // wfA: 16 ntg * 8 ks * 64 lanes
    int lane = t & 63;
    int ks = (t >> 6) & 7;
    int ntg = t >> 9;
    int col = (ntg << 4) + (lane & 15);
    int kb = (ks << 5) + ((lane >> 4) << 3);
#pragma unroll
    for (int q = 0; q < 8; ++q)
      wfA[t * 8 + q] = f2bf(W2a[(kb + q) * 256 + col]);
  } else if (t < 10240) {  // wfB2: 4 w * 2 t2 * 4 dt * 64 lanes
    int t2i = t - 8192;
    int lane = t2i & 63;
    int dt = (t2i >> 6) & 3;
    int tt = (t2i >> 8) & 1;
    int w = t2i >> 9;
    int g = lane >> 4, c = lane & 15;
    int col = (dt << 4) + c;
#pragma unroll
    for (int q = 0; q < 8; ++q) {
      int pi = (q < 4) ? (g * 4 + q) : (16 + g * 4 + (q - 4));
      int n = w * 64 + tt * 32 + pi;
      wfB2[t2i * 8 + q] = f2bf(W2b[n * 64 + col]);
    }
  }
}

// ---------------------------------------------------------------------------
// out1: R1-proven, SEPARATE kernel (fusion thrashes cache: R4/R5/R11).
// Launched before out2 (puts emb2 -- 134 MB, L3-fits -- into L3).
// ---------------------------------------------------------------------------
__global__ __launch_bounds__(256) void out1_kernel(
    const float* __restrict__ emb1, const float* __restrict__ emb2,
    const float* __restrict__ W1a, const float* __restrict__ b1a,
    const float* __restrict__ W1b, const float* __restrict__ b1b,
    float* __restrict__ out1) {
  int bi = blockIdx.x;
  int t = threadIdx.x;
  __shared__ float smax[4][64];
  __shared__ float smin[4][64];
  __shared__ float cat1[192];
  __shared__ float h[128];

  int d = t & 63, q = t >> 6;
  const float* base = emb2 + (size_t)bi * 256 * 64;
  float vmax = -INFINITY, vmin = INFINITY;
  for (int j = q; j < 256; j += 4) {
    float v = base[j * 64 + d];
    vmax = fmaxf(vmax, v);
    vmin = fminf(vmin, v);
  }
  smax[q][d] = vmax;
  smin[q][d] = vmin;
  __syncthreads();
  if (t < 64) {
    float mx = fmaxf(fmaxf(smax[0][t], smax[1][t]), fmaxf(smax[2][t], smax[3][t]));
    float mn = fminf(fminf(smin[0][t], smin[1][t]), fminf(smin[2][t], smin[3][t]));
    cat1[t] = emb1[bi * 64 + t];
    cat1[64 + t] = mx;
    cat1[128 + t] = mn;
  }
  __syncthreads();
  if (t < 128) {
    float acc = b1a[t];
    for (int k = 0; k < 192; ++k) acc += cat1[k] * W1a[k * 128 + t];
    h[t] = fmaxf(acc, 0.f);
  }
  __syncthreads();
  if (t < 64) {
    float acc = b1b[t];
    for (int k = 0; k < 128; ++k) acc += h[k] * W1b[k * 64 + t];
    out1[bi * 64 + t] = acc;
  }
}

// ---------------------------------------------------------------------------
// out2: R12 skeleton + EXPLICIT LOAD PIPELINING (the single change).
// R12's VGPR=72 shows the compiler allocated no prefetch buffers: each GEMM1
// k-step serialized wait-wfA(~200cy L2) -> 16 MFMA(80cy). Fix:
//  - GEMM1: depth-1 double-buffer of wfA frags (global) and X frags (LDS);
//    loads for ks+1 issue before the MFMAs of ks. Static indices via unroll.
//  - GEMM2: all 8 wfB2 frags hoisted before the pack VALU.
// Everything else bit-identical to R12 (stage, exchange, store, grid).
// __launch_bounds__(256,2); expected VGPR ~130-165 (3 waves/SIMD, above the
// measured 2.4 residency). Spill tripwire: WRITE_SIZE > 131072 KB.
// ---------------------------------------------------------------------------
__global__ __launch_bounds__(256, 2) void out2_kernel(
    const float* __restrict__ emb1, const float* __restrict__ emb2,
    const float* __restrict__ b2a, const float* __restrict__ b2b,
    const u16* __restrict__ wfA, const u16* __restrict__ wfB2,
    float* __restrict__ out2) {
  __shared__ __align__(16) u16 SH[16384];  // 32 KB

  int blk = blockIdx.x;
  int b = blk >> 10;
  int i = (blk >> 2) & 255;
  int j0 = (blk & 3) << 6;
  int t = threadIdx.x;
  int lane = t & 63;
  int w = t >> 6;
  int lr = lane & 15;
  int lg = lane >> 4;

  // ---- stage X: 64 rows x 256 bf16 (512B rows), swizzle byte^=(r&7)<<4 ----
  {
    int r = t >> 2;
    int c16 = (t & 3) << 4;
    const float* s0 = emb1 + ((b << 8) + j0 + r) * 64;
    const float* s1 = emb2 + ((((size_t)(b << 8) + j0 + r) << 8) + i) * 64;
    const float* s2 = emb1 + ((b << 8) + i) * 64;
    const float* s3 = emb2 + ((((size_t)(b << 8) + i) << 8) + (j0 + r)) * 64;
    const float* srcs[4] = {s0, s1, s2, s3};
#pragma unroll
    for (int seg = 0; seg < 4; ++seg) {
      const float* src = srcs[seg];
#pragma unroll
      for (int u = 0; u < 2; ++u) {
        int d = c16 + (u << 3);
        float4 v0 = *(const float4*)(src + d);
        float4 v1 = *(const float4*)(src + d + 4);
        u16x8 o = {cvt_bf16(v0.x), cvt_bf16(v0.y), cvt_bf16(v0.z), cvt_bf16(v0.w),
                   cvt_bf16(v1.x), cvt_bf16(v1.y), cvt_bf16(v1.z), cvt_bf16(v1.w)};
        int byteOff = (r * 512 + ((seg << 6) + d) * 2) ^ ((r & 7) << 4);
        *(u16x8*)((char*)SH + byteOff) = o;
      }
    }
  }
  __syncthreads();

  // ---- GEMM1 (swapped, depth-1 pipelined): acc1[m][nt][e]:
  //      j = j0+16m+lr, n = 64w+16nt+4lg+e ----
  f32x4 acc1[4][4];
#pragma unroll
  for (int m = 0; m < 4; ++m)
#pragma unroll
    for (int nt = 0; nt < 4; ++nt) acc1[m][nt] = (f32x4){0.f, 0.f, 0.f, 0.f};

  bf16x8 aF[2][4], bF[2][4];
  // preload ks = 0
#pragma unroll
  for (int nt = 0; nt < 4; ++nt)
    bF[0][nt] = ld_frag_glb(wfA + (size_t)((((w << 2) + nt) * 8 + 0) * 64 + lane) * 8);
#pragma unroll
  for (int m = 0; m < 4; ++m)
    aF[0][m] = ld_frag_lds(SH, (((m << 4) + lr) * 512 + (lg << 4)) ^ ((lr & 7) << 4));

#pragma unroll
  for (int ks = 0; ks < 8; ++ks) {
    const int cur = ks & 1;
    const int nxt = cur ^ 1;
    if (ks < 7) {  // issue ks+1 loads BEFORE the MFMAs of ks
      int kByte = ((ks + 1) << 6) + (lg << 4);
#pragma unroll
      for (int nt = 0; nt < 4; ++nt)
        bF[nxt][nt] = ld_frag_glb(wfA + (size_t)((((w << 2) + nt) * 8 + (ks + 1)) * 64 + lane) * 8);
#pragma unroll
      for (int m = 0; m < 4; ++m)
        aF[nxt][m] = ld_frag_lds(SH, (((m << 4) + lr) * 512 + kByte) ^ ((lr & 7) << 4));
    }
#pragma unroll
    for (int m = 0; m < 4; ++m)
#pragma unroll
      for (int nt = 0; nt < 4; ++nt)
        acc1[m][nt] = __builtin_amdgcn_mfma_f32_16x16x32_bf16(bF[cur][nt], aF[cur][m],
                                                              acc1[m][nt], 0, 0, 0);
  }

  __syncthreads();  // all X reads done; SH becomes the exchange region

  // ---- GEMM2 in registers (pi-packing, R12-proven), wfB2 frags hoisted ----
  bf16x8 wfb[8];
#pragma unroll
  for (int t2 = 0; t2 < 2; ++t2)
#pragma unroll
    for (int dt = 0; dt < 4; ++dt)
      wfb[t2 * 4 + dt] =
          ld_frag_glb(wfB2 + (size_t)(((((w << 1) + t2) << 2) + dt) * 64 + lane) * 8);

  f32x4 acc2[4][4];  // [m][dt]: d = 16dt+4lg+e, j = j0+16m+lr
#pragma unroll
  for (int m = 0; m < 4; ++m)
#pragma unroll
    for (int dt = 0; dt < 4; ++dt) acc2[m][dt] = (f32x4){0.f, 0.f, 0.f, 0.f};

#pragma unroll
  for (int t2 = 0; t2 < 2; ++t2) {
    int nbase = (w << 6) + (t2 << 5) + (lg << 2);
    float4 ba = *(const float4*)(b2a + nbase);
    float4 bb = *(const float4*)(b2a + nbase + 16);
    bf16x8 h[4];
#pragma unroll
    for (int m = 0; m < 4; ++m) {
      f32x4 pa = acc1[m][2 * t2];
      f32x4 pb = acc1[m][2 * t2 + 1];
      u16x8 hp = {cvt_bf16(fmaxf(pa[0] + ba.x, 0.f)), cvt_bf16(fmaxf(pa[1] + ba.y, 0.f)),
                  cvt_bf16(fmaxf(pa[2] + ba.z, 0.f)), cvt_bf16(fmaxf(pa[3] + ba.w, 0.f)),
                  cvt_bf16(fmaxf(pb[0] + bb.x, 0.f)), cvt_bf16(fmaxf(pb[1] + bb.y, 0.f)),
                  cvt_bf16(fmaxf(pb[2] + bb.z, 0.f)), cvt_bf16(fmaxf(pb[3] + bb.w, 0.f))};
      h[m] = __builtin_bit_cast(bf16x8, hp);
    }
#pragma unroll
    for (int dt = 0; dt < 4; ++dt) {
#pragma unroll
      for (int m = 0; m < 4; ++m)
        acc2[m][dt] = __builtin_amdgcn_mfma_f32_16x16x32_bf16(wfb[t2 * 4 + dt], h[m],
                                                              acc2[m][dt], 0, 0, 0);
    }
  }

  // ---- cross-wave reduction, BF16 partials: 12 tiles x 512B = 24 KB ----
  char* red = (char*)SH;
#pragma unroll
  for (int dt = 0; dt < 4; ++dt) {
    if (dt != w) {
      int s = dt - (dt > w ? 1 : 0);
#pragma unroll
      for (int m = 0; m < 4; ++m) {
        f32x4 p = acc2[m][dt];
        u16x4 o = {cvt_bf16(p[0]), cvt_bf16(p[1]), cvt_bf16(p[2]), cvt_bf16(p[3])};
        *(u16x4*)(red + (((w * 12 + s * 4 + m) << 9) + (lane << 3))) = o;
      }
    }
  }
  __syncthreads();

  // own tile (static-index select) + peers' bf16 partials
  f32x4 accO[4];
#pragma unroll
  for (int m = 0; m < 4; ++m) {
    accO[m] = acc2[m][0];
#pragma unroll
    for (int dt = 1; dt < 4; ++dt)
      if (w == dt) accO[m] = acc2[m][dt];
  }
#pragma unroll
  for (int wp = 0; wp < 4; ++wp) {
    if (wp != w) {
      int s = w - (w > wp ? 1 : 0);
#pragma unroll
      for (int m = 0; m < 4; ++m) {
        u16x4 o = *(const u16x4*)(red + (((wp * 12 + s * 4 + m) << 9) + (lane << 3)));
        accO[m][0] += bf2f(o[0]);
        accO[m][1] += bf2f(o[1]);
        accO[m][2] += bf2f(o[2]);
        accO[m][3] += bf2f(o[3]);
      }
    }
  }

  // ---- store: j = j0+16m+lr, d = 16w+4lg+e ----
  float4 bias2 = *(const float4*)(b2b + (w << 4) + (lg << 2));
  float* obase = out2 + (((size_t)(b << 8) + i) * 256 + j0) * 64 + (w << 4) + (lg << 2);
#pragma unroll
  for (int m = 0; m < 4; ++m) {
    float4 v = {accO[m][0] + bias2.x, accO[m][1] + bias2.y,
                accO[m][2] + bias2.z, accO[m][3] + bias2.w};
    *(float4*)(obase + (size_t)((m << 4) + lr) * 64) = v;
  }
}

extern "C" void kernel_launch(void* const* d_in, const int* in_sizes, int n_in,
                              void* d_out, int out_size, void* d_ws, size_t ws_size,
                              hipStream_t stream) {
  const float* emb1 = (const float*)d_in[0];
  const float* emb2 = (const float*)d_in[1];
  const float* W1a  = (const float*)d_in[2];
  const float* b1a  = (const float*)d_in[3];
  const float* W1b  = (const float*)d_in[4];
  const float* b1b  = (const float*)d_in[5];
  const float* W2a  = (const float*)d_in[6];
  const float* b2a  = (const float*)d_in[7];
  const float* W2b  = (const float*)d_in[8];
  const float* b2b  = (const float*)d_in[9];

  float* out = (float*)d_out;
  u16* wfA  = (u16*)d_ws;            // 16*8*64*8 = 65536 u16 = 128 KB
  u16* wfB2 = wfA + 65536;           //  4*2*4*64*8 = 16384 u16 = 32 KB

  prep_w_kernel<<<40, 256, 0, stream>>>(W2a, W2b, wfA, wfB2);
  // out1 first: its full emb2 scan leaves emb2 (134 MB) L3-resident
  out1_kernel<<<2048, 256, 0, stream>>>(emb1, emb2, W1a, b1a, W1b, b1b, out);
  out2_kernel<<<8192, 256, 0, stream>>>(emb1, emb2, b2a, b2b, wfA, wfB2,
                                        out + 8 * 256 * 64);
}